// Round 17
// baseline (1144.558 us; speedup 1.0000x reference)
//
#include <hip/hip_runtime.h>
#include <math.h>

// LDGCNN forward: 4 EdgeConv blocks (knn K=20) + 1x1 conv block + global max pool + 3 FC.
// B=8, N=2048. Feature buffer X: (B, N, XS) rows, columns [pts(3)|f1(64)|f2(64)|f3(64)|f4(128)].
// XS=324 keeps rows 16B-aligned for float4 loads (column 323 is an unused pad).
//
// R17: EdgeConv linearized: h[n,k,o] = H[idx[n,k],o] + G[n,o] -> dense GEMM + gather+max.
// R19/R24: k_stage5 RB=32 + wave-uniform scalar X loads (LDS=0). R23: k_dist float4 B-frags.
// R25: k_select radix-select (set semantics; downstream max-pool is order-invariant):
// 152 -> <135us/launch; total 1349 -> 1048.
// R26 (this round): k_dist double-buffered staging. Old: {global-load -> barrier -> compute
// -> barrier} per 16-ch chunk left ~600cyc global latency exposed at ~2 blocks/CU (135us vs
// 66us max-pipe floor, VALUBusy 47%). New: prefetch chunk i+1 into REGISTERS before compute
// of chunk i, ds-write to alternate buffer after compute, ONE barrier/chunk. Staging LDS
// 16->32KB (T overlays), +16 VGPR prefetch regs.

constexpr int BB = 8;
constexpr int NN = 2048;
constexpr int KK = 20;
constexpr int CT = 323;
constexpr int XS = 324;
constexpr int X4S = XS / 4;   // 81 float4 per row
constexpr float NEGS = 0.2f;

__device__ __forceinline__ float lrelu(float v) { return v > 0.0f ? v : NEGS * v; }

__device__ __forceinline__ void atomicMaxF(float* addr, float v) {
    if (v >= 0.0f) atomicMax((int*)addr, __float_as_int(v));
    else           atomicMin((unsigned int*)addr, __float_as_uint(v));
}

__device__ __forceinline__ void fma4(float4& a, float x, const float4 w) {
    a.x = fmaf(x, w.x, a.x); a.y = fmaf(x, w.y, a.y);
    a.z = fmaf(x, w.z, a.z); a.w = fmaf(x, w.w, a.w);
}

// ---- fused prep: WT packs + W5T transpose + gfeat init + transpose/sq0 + X zero-fill -----
constexpr int WTOT = 19072;
__global__ void k_prep_all(const float* __restrict__ W1, const float* __restrict__ W2,
                           const float* __restrict__ W3, const float* __restrict__ W4,
                           const float* __restrict__ W5, const float* __restrict__ x,
                           float4* __restrict__ WT4, float* __restrict__ W5T,
                           float* __restrict__ gfeat, float* __restrict__ X,
                           float* __restrict__ sq) {
    int j = blockIdx.x * blockDim.x + threadIdx.x;
    if (j < WTOT) {
        int base, Cout, C;
        const float* W;
        if (j < 128)       { base = 0;    Cout = 64;  C = 3;   W = W1; }
        else if (j < 2304) { base = 128;  Cout = 64;  C = 67;  W = W2; }
        else if (j < 6528) { base = 2304; Cout = 64;  C = 131; W = W3; }
        else               { base = 6528; Cout = 128; C = 195; W = W4; }
        int W4w = Cout / 2;                 // 2*Cout/4 float4 groups per channel row
        int local = j - base;
        int c = local / W4w, og = local - c * W4w;
        float v[4];
#pragma unroll
        for (int q = 0; q < 4; ++q) {
            int o2 = 4 * og + q;
            if (c >= C) v[q] = 0.f;
            else if (o2 < Cout) v[q] = W[(size_t)o2 * 2 * C + c];
            else {
                int o = o2 - Cout;
                v[q] = W[(size_t)o * 2 * C + C + c] - W[(size_t)o * 2 * C + c];
            }
        }
        WT4[j] = make_float4(v[0], v[1], v[2], v[3]);
    } else if (j < WTOT + XS * 1024) {
        int t = j - WTOT;
        int c = t / 1024, o = t % 1024;
        W5T[t] = (c < CT) ? W5[(size_t)o * CT + c] : 0.f;   // row 323 zeroed
    } else if (j < WTOT + XS * 1024 + BB * 1024) {
        gfeat[j - WTOT - XS * 1024] = -INFINITY;
    } else if (j < WTOT + XS * 1024 + BB * 1024 + BB * NN) {
        int i = j - WTOT - XS * 1024 - BB * 1024;            // b*NN + n
        int b = i >> 11, n = i & 2047;
        const float* xb = x + (size_t)b * 3 * NN;
        float vx = xb[n], vy = xb[NN + n], vz = xb[2 * NN + n];
        float* row = X + (size_t)i * XS;
        row[0] = vx; row[1] = vy; row[2] = vz; row[3] = 0.f;
        sq[i] = vx * vx + vy * vy + vz * vz;
    } else if (j < WTOT + XS * 1024 + BB * 1024 + BB * NN + BB * NN * 80) {
        // zero-fill X feature columns (float4 indices 1..80 of each row; col 3 done above)
        int t = j - (WTOT + XS * 1024 + BB * 1024 + BB * NN);
        int row = t / 80, c4 = 1 + (t - 80 * row);
        ((float4*)X)[(size_t)row * X4S + c4] = make_float4(0.f, 0.f, 0.f, 0.f);
    }
}

// ---- dist[b][n][m] = max(sq_n + sq_m - 2*dot, 0) — SYMMETRIC: only tiles ti>=tj ----------
// 128x128 tile, 8x8 per thread. R26: double-buffered staging — prefetch chunk i+1 into
// registers during compute of chunk i, ds-write after, ONE barrier per chunk (was 2; hides
// global latency). Off-diagonal: direct float4 writes + mirrored 4-pass LDS transpose.
constexpr int TM = 128;
__global__ __launch_bounds__(256) void k_dist(const float* __restrict__ X,
                                              const float* __restrict__ sq,
                                              float* __restrict__ dist, int C) {
    int b = blockIdx.z;
    int blk = blockIdx.x;                 // 0..135 -> (ti, tj), ti >= tj
    int ti = (int)((sqrtf(8.0f * blk + 1.0f) - 1.0f) * 0.5f);
    while ((ti + 1) * (ti + 2) / 2 <= blk) ++ti;
    while (ti * (ti + 1) / 2 > blk) --ti;
    int tj = blk - ti * (ti + 1) / 2;
    int m0 = ti * TM;                     // col tile
    int n0 = tj * TM;                     // row tile
    __shared__ float smem[8192];          // 32 KB: 2x {As[16][128], Bs[16][128]}; T overlays
    int tid = threadIdx.x;
    int tx = tid & 15;        // cols: m0 + h*64 + tx*4 + jj  (j = 4h+jj)
    int ty = tid >> 4;        // rows: n0 + ty*8 + i
    float acc[8][8] = {};
    const float* Xb = X + (size_t)b * NN * XS;
    int sr = tid & 127;       // staging row
    int sc0 = (tid >> 7) * 8; // staging channel half (0 or 8)
    float av[8], bvp[8];      // prefetch registers
    auto loadChunk = [&](int c0) {
        const float* arow = Xb + (size_t)(n0 + sr) * XS + c0 + sc0;
        const float* brow = Xb + (size_t)(m0 + sr) * XS + c0 + sc0;
        float4 a0 = *(const float4*)(arow);
        float4 a1 = *(const float4*)(arow + 4);
        float4 b0 = *(const float4*)(brow);
        float4 b1 = *(const float4*)(brow + 4);
        av[0] = a0.x; av[1] = a0.y; av[2] = a0.z; av[3] = a0.w;
        av[4] = a1.x; av[5] = a1.y; av[6] = a1.z; av[7] = a1.w;
        bvp[0] = b0.x; bvp[1] = b0.y; bvp[2] = b0.z; bvp[3] = b0.w;
        bvp[4] = b1.x; bvp[5] = b1.y; bvp[6] = b1.z; bvp[7] = b1.w;
    };
    auto writeChunk = [&](int buf, int c0) {
        float* As = smem + buf * 4096;
        float* Bs = As + 2048;
#pragma unroll
        for (int i = 0; i < 8; ++i) {
            bool inr = (c0 + sc0 + i) < C;
            As[(sc0 + i) * TM + sr] = inr ? av[i] : 0.f;
            Bs[(sc0 + i) * TM + sr] = inr ? bvp[i] : 0.f;
        }
    };
    int nch = (C + 15) / 16;
    loadChunk(0);
    writeChunk(0, 0);
    __syncthreads();
    for (int ch = 0; ch < nch; ++ch) {
        if (ch + 1 < nch) loadChunk(16 * (ch + 1));   // issue early: hidden under compute
        const float* As = smem + (ch & 1) * 4096;
        const float* Bs = As + 2048;
#pragma unroll
        for (int cc = 0; cc < 16; ++cc) {
            float4 a0r = *(const float4*)&As[cc * TM + ty * 8];
            float4 a1r = *(const float4*)&As[cc * TM + ty * 8 + 4];
            float a[8] = {a0r.x, a0r.y, a0r.z, a0r.w, a1r.x, a1r.y, a1r.z, a1r.w};
            float4 b0r = *(const float4*)&Bs[cc * TM + tx * 4];
            float4 b1r = *(const float4*)&Bs[cc * TM + 64 + tx * 4];
            float bv[8] = {b0r.x, b0r.y, b0r.z, b0r.w, b1r.x, b1r.y, b1r.z, b1r.w};
#pragma unroll
            for (int i = 0; i < 8; ++i)
#pragma unroll
                for (int j = 0; j < 8; ++j)
                    acc[i][j] = fmaf(a[i], bv[j], acc[i][j]);
        }
        if (ch + 1 < nch) writeChunk((ch + 1) & 1, 16 * (ch + 1));
        __syncthreads();                  // protects next-buf write & next compute read
    }
    const float* sqb = sq + b * NN;
    float* db = dist + (size_t)b * NN * NN;
    float sm[8];
#pragma unroll
    for (int j = 0; j < 8; ++j) sm[j] = sqb[m0 + (j >> 2) * 64 + tx * 4 + (j & 3)];
#pragma unroll
    for (int i = 0; i < 8; ++i) {
        int n = n0 + ty * 8 + i;
        float sn = sqb[n];
#pragma unroll
        for (int j = 0; j < 8; ++j) {
            float d = fmaxf(sn + sm[j] - 2.f * acc[i][j], 0.f);
            acc[i][j] = d;                                   // keep for mirror
        }
        *(float4*)&db[(size_t)n * NN + m0 + tx * 4] =
            make_float4(acc[i][0], acc[i][1], acc[i][2], acc[i][3]);
        *(float4*)&db[(size_t)n * NN + m0 + 64 + tx * 4] =
            make_float4(acc[i][4], acc[i][5], acc[i][6], acc[i][7]);
    }
    if (ti != tj) {
        // mirrored tile: rows m0.., cols n0.. — 4 passes (h: col half, p2: 32-row group)
        float* T = smem;                  // [32][129]
        int r = tid >> 3;                 // 0..31
        int c0r = (tid & 7) * 16;         // 0..112
#pragma unroll
        for (int h = 0; h < 2; ++h) {
#pragma unroll
            for (int p2 = 0; p2 < 2; ++p2) {
                __syncthreads();          // protect staging/previous pass reads
                if ((tx >> 3) == p2) {    // tx in [8*p2, 8*p2+8): m_local in [32p2, 32p2+32)
#pragma unroll
                    for (int jj = 0; jj < 4; ++jj)
#pragma unroll
                        for (int i = 0; i < 8; ++i)
                            T[((tx & 7) * 4 + jj) * 129 + ty * 8 + i] = acc[i][h * 4 + jj];
                }
                __syncthreads();
                float v[16];
#pragma unroll
                for (int k = 0; k < 16; ++k) v[k] = T[r * 129 + c0r + k];
                float* dst = db + (size_t)(m0 + h * 64 + 32 * p2 + r) * NN + n0 + c0r;
#pragma unroll
                for (int k = 0; k < 4; ++k)
                    *(float4*)(dst + 4 * k) = make_float4(v[4 * k], v[4 * k + 1],
                                                          v[4 * k + 2], v[4 * k + 3]);
            }
        }
    }
}

// ---- top-K smallest per row (SET semantics — downstream is max-pool, order-invariant) ----
// key = (bits(d)<<11)|m (unique; ties -> lower m, matching lax.top_k). Radix-select the
// exact 20th-smallest key T, then emit all keys <= T (exactly 20, arbitrary order).
__global__ __launch_bounds__(128) void k_select(const float* __restrict__ dist,
                                                int* __restrict__ idx) {
    int bn = blockIdx.x;   // b*NN + n
    int tid = threadIdx.x;
    int wv = tid >> 6;
    int lane = tid & 63;
    const float* drow = dist + (size_t)bn * NN;
    int m0 = tid * 16;
    unsigned long long keys[16];
#pragma unroll
    for (int i = 0; i < 4; ++i) {
        float4 v = *(const float4*)(drow + m0 + 4 * i);
        keys[4 * i + 0] = ((unsigned long long)__float_as_uint(v.x) << 11) | (unsigned)(m0 + 4 * i + 0);
        keys[4 * i + 1] = ((unsigned long long)__float_as_uint(v.y) << 11) | (unsigned)(m0 + 4 * i + 1);
        keys[4 * i + 2] = ((unsigned long long)__float_as_uint(v.z) << 11) | (unsigned)(m0 + 4 * i + 2);
        keys[4 * i + 3] = ((unsigned long long)__float_as_uint(v.w) << 11) | (unsigned)(m0 + 4 * i + 3);
    }
    // Bound B: per-lane min16 -> wave max of minima -> min over waves. Each wave has 64
    // keys (its lane minima) <= its own bound, so >=64 keys <= B => T(20th) <= B.
    unsigned long long mn = keys[0];
#pragma unroll
    for (int i = 1; i < 16; ++i) mn = keys[i] < mn ? keys[i] : mn;
    unsigned long long mx = mn;
#pragma unroll
    for (int s = 1; s < 64; s <<= 1) {
        unsigned long long o = (unsigned long long)__shfl_xor((long long)mx, s, 64);
        mx = o > mx ? o : mx;
    }
    __shared__ unsigned long long sB[2];
    __shared__ unsigned long long sT;
    __shared__ int sWant;
    __shared__ int sCnt;
    __shared__ int hist[256];
    if (lane == 0) sB[wv] = mx;
    if (tid == 0) { sT = 0ull; sWant = KK; sCnt = 0; }
    __syncthreads();
    unsigned long long B = sB[0] < sB[1] ? sB[0] : sB[1];
    // 6-level byte-wise radix descent over the 43-bit key (levels cover bits [47:0]).
#pragma unroll 1
    for (int level = 0; level < 6; ++level) {
        int sh = 40 - 8 * level;
        hist[tid] = 0; hist[tid + 128] = 0;
        __syncthreads();
        unsigned long long pref = sT;
#pragma unroll
        for (int i = 0; i < 16; ++i) {
            unsigned long long k = keys[i];
            if (k <= B && (k >> (sh + 8)) == (pref >> (sh + 8)))
                atomicAdd(&hist[(int)((k >> sh) & 255)], 1);
        }
        __syncthreads();
        if (tid < 64) {
            int h0 = hist[4 * tid], h1 = hist[4 * tid + 1];
            int h2 = hist[4 * tid + 2], h3 = hist[4 * tid + 3];
            int s = h0 + h1 + h2 + h3;
            int inc = s;
#pragma unroll
            for (int d = 1; d < 64; d <<= 1) {
                int o = __shfl_up(inc, d, 64);
                if (lane >= d) inc += o;
            }
            int want = sWant;
            int c = inc - s;              // exclusive prefix
            int bsel = -1, rem = 0;
            if (c < want && want <= c + h0) { bsel = 4 * tid + 0; rem = want - c; } c += h0;
            if (bsel < 0 && c < want && want <= c + h1) { bsel = 4 * tid + 1; rem = want - c; } c += h1;
            if (bsel < 0 && c < want && want <= c + h2) { bsel = 4 * tid + 2; rem = want - c; } c += h2;
            if (bsel < 0 && c < want && want <= c + h3) { bsel = 4 * tid + 3; rem = want - c; }
            if (bsel >= 0) {
                sT = pref | ((unsigned long long)bsel << sh);
                sWant = rem;
            }
        }
        __syncthreads();
    }
    unsigned long long T = sT;            // exact 20th-smallest key
    int* orow = idx + (size_t)bn * KK;
#pragma unroll
    for (int i = 0; i < 16; ++i) {
        if (keys[i] <= T) {
            int s = atomicAdd(&sCnt, 1);
            orow[s] = (int)(keys[i] & 2047u);
        }
    }
}

// ---- k_hg: H = X.Wa^T, G = X.Wd^T — dense GEMM, no gather. -------------------------------
template <int KC4, int COUT>
__global__ __launch_bounds__(256)
void k_hg(const float* __restrict__ X, const float4* __restrict__ WT4,
          float* __restrict__ H, float* __restrict__ G) {
    constexpr int W4 = COUT / 2;            // 2*COUT/4 float4 outputs per channel row
    constexpr int RB2 = 32;
    constexpr int RPT = RB2 * W4 / 256;     // rows per thread (8 for COUT=128, 4 for 64)
    int bn0 = blockIdx.x * RB2;
    __shared__ float4 xs[RB2][KC4];
    int tid = threadIdx.x;
    const float4* X4 = (const float4*)X;
    for (int j = tid; j < RB2 * KC4; j += 256) {
        int r = j / KC4, c = j - r * KC4;
        xs[r][c] = X4[(size_t)(bn0 + r) * X4S + c];
    }
    __syncthreads();
    int og = tid & (W4 - 1);
    int rg = tid / W4;                      // row group
    float4 acc[RPT];
#pragma unroll
    for (int i = 0; i < RPT; ++i) acc[i] = make_float4(0.f, 0.f, 0.f, 0.f);
#pragma unroll 2
    for (int c4 = 0; c4 < KC4; ++c4) {
        float4 w0 = WT4[(size_t)(4 * c4 + 0) * W4 + og];
        float4 w1 = WT4[(size_t)(4 * c4 + 1) * W4 + og];
        float4 w2 = WT4[(size_t)(4 * c4 + 2) * W4 + og];
        float4 w3 = WT4[(size_t)(4 * c4 + 3) * W4 + og];
#pragma unroll
        for (int i = 0; i < RPT; ++i) {
            float4 xv = xs[rg * RPT + i][c4];
            fma4(acc[i], xv.x, w0);
            fma4(acc[i], xv.y, w1);
            fma4(acc[i], xv.z, w2);
            fma4(acc[i], xv.w, w3);
        }
    }
    int o2 = 4 * og;
#pragma unroll
    for (int i = 0; i < RPT; ++i) {
        int bn = bn0 + rg * RPT + i;
        if (o2 < COUT) *(float4*)&H[(size_t)bn * COUT + o2] = acc[i];
        else           *(float4*)&G[(size_t)bn * COUT + (o2 - COUT)] = acc[i];
    }
}

// ---- k_edgemax: X[bn, outoff+o] = max_k lrelu((H[idx[bn,k],o] + G[bn,o])*s+b) ------------
template <int COUT>
__global__ __launch_bounds__(256)
void k_edgemax(const float* __restrict__ H, const float* __restrict__ G,
               const int* __restrict__ idx, const float* __restrict__ scale,
               const float* __restrict__ bias, int outoff,
               float* __restrict__ X, float* __restrict__ sq) {
    constexpr int CPL = COUT / 64;          // cols per lane (1 or 2)
    int wv = threadIdx.x >> 6, lane = threadIdx.x & 63;
    int bn = blockIdx.x * 4 + wv;
    int b = bn >> 11;                       // NN = 2048
    int id = idx[(size_t)bn * KK + (lane < KK ? lane : 0)];
    float gv[CPL], sv[CPL], bv[CPL], mx[CPL];
#pragma unroll
    for (int q = 0; q < CPL; ++q) {
        int o = lane + 64 * q;
        gv[q] = G[(size_t)bn * COUT + o];
        sv[q] = scale[o];
        bv[q] = bias[o];
        mx[q] = -INFINITY;
    }
#pragma unroll
    for (int k = 0; k < KK; ++k) {
        int m = __shfl(id, k, 64);
        const float* hrow = H + (size_t)(b * NN + m) * COUT;
#pragma unroll
        for (int q = 0; q < CPL; ++q) {
            float v = hrow[lane + 64 * q] + gv[q];
            mx[q] = fmaxf(mx[q], lrelu(v * sv[q] + bv[q]));
        }
    }
    float* orow = X + (size_t)bn * XS + outoff;
    float v = 0.f;
#pragma unroll
    for (int q = 0; q < CPL; ++q) {
        orow[lane + 64 * q] = mx[q];
        v = fmaf(mx[q], mx[q], v);
    }
#pragma unroll
    for (int s = 1; s < 64; s <<= 1) v += __shfl_xor(v, s, 64);
    if (lane == 0) sq[bn] += v;
}

// ---- block5: g = lrelu((X . W5^T)*s5+b5), atomic max over n into gfeat -------------------
// R24 (kept): wave-uniform global X reads via readfirstlane (scalar pipe), LDS=0.
constexpr int RB = 32;
__global__ __launch_bounds__(512) void k_stage5(const float* __restrict__ X,
                                                const float* __restrict__ W5T,
                                                const float* __restrict__ s5,
                                                const float* __restrict__ b5,
                                                float* __restrict__ gfeat) {
    int blk = blockIdx.x;
    int b = blk / (NN / RB);
    int n0 = (blk % (NN / RB)) * RB;
    int tid = threadIdx.x;
    const float4* X4 = (const float4*)X;
    const float4* W5T4 = (const float4*)W5T;   // [XS][256] float4 per row
    int og = tid & 255;                   // output float4 slot (4 outputs)
    int r0 = __builtin_amdgcn_readfirstlane((tid >> 8) * 16);  // wave-uniform row group
    const float4* xrows = X4 + (size_t)(b * NN + n0 + r0) * X4S;
    float acc[16][4] = {};
    for (int c4 = 0; c4 < X4S; ++c4) {
        float4 w0 = W5T4[(size_t)(4 * c4 + 0) * 256 + og];
        float4 w1 = W5T4[(size_t)(4 * c4 + 1) * 256 + og];
        float4 w2 = W5T4[(size_t)(4 * c4 + 2) * 256 + og];
        float4 w3 = W5T4[(size_t)(4 * c4 + 3) * 256 + og];
#pragma unroll
        for (int r = 0; r < 16; ++r) {
            float4 a = xrows[(size_t)r * X4S + c4];   // uniform addr -> scalar load
            acc[r][0] = fmaf(a.x, w0.x, acc[r][0]);
            acc[r][1] = fmaf(a.x, w0.y, acc[r][1]);
            acc[r][2] = fmaf(a.x, w0.z, acc[r][2]);
            acc[r][3] = fmaf(a.x, w0.w, acc[r][3]);
            acc[r][0] = fmaf(a.y, w1.x, acc[r][0]);
            acc[r][1] = fmaf(a.y, w1.y, acc[r][1]);
            acc[r][2] = fmaf(a.y, w1.z, acc[r][2]);
            acc[r][3] = fmaf(a.y, w1.w, acc[r][3]);
            acc[r][0] = fmaf(a.z, w2.x, acc[r][0]);
            acc[r][1] = fmaf(a.z, w2.y, acc[r][1]);
            acc[r][2] = fmaf(a.z, w2.z, acc[r][2]);
            acc[r][3] = fmaf(a.z, w2.w, acc[r][3]);
            acc[r][0] = fmaf(a.w, w3.x, acc[r][0]);
            acc[r][1] = fmaf(a.w, w3.y, acc[r][1]);
            acc[r][2] = fmaf(a.w, w3.z, acc[r][2]);
            acc[r][3] = fmaf(a.w, w3.w, acc[r][3]);
        }
    }
    int o0 = og * 4;
#pragma unroll
    for (int i = 0; i < 4; ++i) {
        int o = o0 + i;
        float s = s5[o], bbv = b5[o];
        float mx = -INFINITY;
#pragma unroll
        for (int r = 0; r < 16; ++r) {
            float v = lrelu(acc[r][i] * s + bbv);
            mx = fmaxf(v, mx);
        }
        atomicMaxF(&gfeat[b * 1024 + o], mx);
    }
}

// ---- fused FC head: fc1 -> fc2 -> fc3 per batch row, intermediates in LDS ----------------
__global__ __launch_bounds__(256) void k_fc(const float* __restrict__ gfeat,
                                            const float* __restrict__ fW1, const float* __restrict__ fb1,
                                            const float* __restrict__ fs1, const float* __restrict__ fB1,
                                            const float* __restrict__ fW2, const float* __restrict__ fb2,
                                            const float* __restrict__ fs2, const float* __restrict__ fB2,
                                            const float* __restrict__ fW3, const float* __restrict__ fb3,
                                            float* __restrict__ logits) {
    int b = blockIdx.x;
    __shared__ float g[1024];
    __shared__ float h1s[512];
    __shared__ float h2s[256];
    int tid = threadIdx.x;
    for (int j = tid; j < 1024; j += 256) g[j] = gfeat[b * 1024 + j];
    __syncthreads();
    for (int o = tid; o < 512; o += 256) {
        const float* wr = fW1 + (size_t)o * 1024;
        float acc = 0.f;
        for (int c = 0; c < 1024; ++c) acc = fmaf(g[c], wr[c], acc);
        h1s[o] = lrelu((acc + fb1[o]) * fs1[o] + fB1[o]);
    }
    __syncthreads();
    {
        int o = tid;
        const float* wr = fW2 + (size_t)o * 512;
        float acc = 0.f;
        for (int c = 0; c < 512; ++c) acc = fmaf(h1s[c], wr[c], acc);
        h2s[o] = lrelu((acc + fb2[o]) * fs2[o] + fB2[o]);
    }
    __syncthreads();
    if (tid < 40) {
        const float* wr = fW3 + (size_t)tid * 256;
        float acc = 0.f;
        for (int c = 0; c < 256; ++c) acc = fmaf(h2s[c], wr[c], acc);
        logits[b * 40 + tid] = acc + fb3[tid];
    }
}

extern "C" void kernel_launch(void* const* d_in, const int* in_sizes, int n_in,
                              void* d_out, int out_size, void* d_ws, size_t ws_size,
                              hipStream_t stream) {
    const float* x   = (const float*)d_in[0];
    const float* W1  = (const float*)d_in[1];
    const float* s1  = (const float*)d_in[2];
    const float* b1  = (const float*)d_in[3];
    const float* W2  = (const float*)d_in[4];
    const float* s2  = (const float*)d_in[5];
    const float* b2  = (const float*)d_in[6];
    const float* W3  = (const float*)d_in[7];
    const float* s3  = (const float*)d_in[8];
    const float* b3  = (const float*)d_in[9];
    const float* W4  = (const float*)d_in[10];
    const float* s4  = (const float*)d_in[11];
    const float* b4  = (const float*)d_in[12];
    const float* W5  = (const float*)d_in[13];
    const float* s5  = (const float*)d_in[14];
    const float* b5  = (const float*)d_in[15];
    const float* fW1 = (const float*)d_in[16];
    const float* fb1 = (const float*)d_in[17];
    const float* fs1 = (const float*)d_in[18];
    const float* fB1 = (const float*)d_in[19];
    const float* fW2 = (const float*)d_in[20];
    const float* fb2 = (const float*)d_in[21];
    const float* fs2 = (const float*)d_in[22];
    const float* fB2 = (const float*)d_in[23];
    const float* fW3 = (const float*)d_in[24];
    const float* fb3 = (const float*)d_in[25];

    float* out    = (float*)d_out;
    float* logits = out;          // 8*40
    float* gfeat  = out + 320;    // 8*1024

    char* ws = (char*)d_ws;
    size_t off = 0;
    auto alloc = [&](size_t bytes) -> void* {
        void* p = ws + off;
        off += (bytes + 255) & ~(size_t)255;
        return p;
    };
    float* X    = (float*)alloc((size_t)BB * NN * XS * 4);      // 21.2 MB
    float* sq   = (float*)alloc((size_t)BB * NN * 4);
    float* dist = (float*)alloc((size_t)BB * NN * NN * 4);      // 134 MB
    int*   idx  = (int*)  alloc((size_t)BB * NN * KK * 4);
    float4* WT4 = (float4*)alloc((size_t)WTOT * 16);            // 305 KB
    float* H    = (float*)alloc((size_t)BB * NN * 128 * 4);     // 8.4 MB
    float* G    = (float*)alloc((size_t)BB * NN * 128 * 4);     // 8.4 MB
    float* W5T  = (float*)alloc((size_t)XS * 1024 * 4);
    (void)ws_size; (void)in_sizes; (void)n_in; (void)out_size;

    // one-shot prep: WT packs + W5T + gfeat init + transpose/sq0 + X zero-fill
    int prepTot = WTOT + XS * 1024 + BB * 1024 + BB * NN + BB * NN * 80;
    k_prep_all<<<(prepTot + 255) / 256, 256, 0, stream>>>(W1, W2, W3, W4, W5, x,
                                                          WT4, W5T, gfeat, X, sq);

    const int Cs[4]    = {3, 67, 131, 195};
    const int offs[4]  = {3, 67, 131, 195};
    const int WOFF[4]  = {0, 128, 2304, 6528};  // channel-row base in packed WT4
    const float* ss[4] = {s1, s2, s3, s4};
    const float* bs[4] = {b1, b2, b3, b4};

    constexpr int NT = NN / TM;                 // 16 tiles per dim
    constexpr int NBLK = NT * (NT + 1) / 2;     // 136 lower-triangle tiles
    for (int st = 0; st < 4; ++st) {
        int C = Cs[st];
        dim3 dg(NBLK, 1, BB);
        k_dist<<<dg, 256, 0, stream>>>(X, sq, dist, C);
        k_select<<<BB * NN, 128, 0, stream>>>(dist, idx);
        const float4* wt = WT4 + WOFF[st];
        switch (st) {
            case 0:
                k_hg<1, 64><<<BB * NN / 32, 256, 0, stream>>>(X, wt, H, G);
                k_edgemax<64><<<BB * NN / 4, 256, 0, stream>>>(H, G, idx, ss[st], bs[st], offs[st], X, sq);
                break;
            case 1:
                k_hg<17, 64><<<BB * NN / 32, 256, 0, stream>>>(X, wt, H, G);
                k_edgemax<64><<<BB * NN / 4, 256, 0, stream>>>(H, G, idx, ss[st], bs[st], offs[st], X, sq);
                break;
            case 2:
                k_hg<33, 64><<<BB * NN / 32, 256, 0, stream>>>(X, wt, H, G);
                k_edgemax<64><<<BB * NN / 4, 256, 0, stream>>>(H, G, idx, ss[st], bs[st], offs[st], X, sq);
                break;
            case 3:
                k_hg<49, 128><<<BB * NN / 32, 256, 0, stream>>>(X, wt, H, G);
                k_edgemax<128><<<BB * NN / 4, 256, 0, stream>>>(H, G, idx, ss[st], bs[st], offs[st], X, sq);
                break;
        }
    }

    k_stage5<<<BB * (NN / RB), 512, 0, stream>>>(X, W5T, s5, b5, gfeat);
    k_fc<<<BB, 256, 0, stream>>>(gfeat, fW1, fb1, fs1, fB1,
                                 fW2, fb2, fs2, fB2, fW3, fb3, logits);
}

// Round 18
// 1010.815 us; speedup vs baseline: 1.1323x; 1.1323x over previous
//
#include <hip/hip_runtime.h>
#include <math.h>

// LDGCNN forward: 4 EdgeConv blocks (knn K=20) + 1x1 conv block + global max pool + 3 FC.
// B=8, N=2048. Feature buffer X: (B, N, XS) rows, columns [pts(3)|f1(64)|f2(64)|f3(64)|f4(128)].
// XS=324 keeps rows 16B-aligned for float4 loads (column 323 is an unused pad).
//
// R17: EdgeConv linearized: h[n,k,o] = H[idx[n,k],o] + G[n,o] -> dense GEMM + gather+max.
// R19/R24: k_stage5 RB=32 + wave-uniform scalar X loads (LDS=0). R23: k_dist float4 B-frags.
// R25: k_select radix-select (set semantics): total 1349 -> 1048.
// R26 (double-buffered k_dist) REGRESSED: VGPR 56->184, occupancy 27->9.6%, 135->219us.
// Rule: lifetime-extending pipelining transforms lose more to VGPR/occupancy than they gain
// in latency hiding on this toolchain. R27 (this round): exact revert to the R16-measured
// kernel (1048us).

constexpr int BB = 8;
constexpr int NN = 2048;
constexpr int KK = 20;
constexpr int CT = 323;
constexpr int XS = 324;
constexpr int X4S = XS / 4;   // 81 float4 per row
constexpr float NEGS = 0.2f;

__device__ __forceinline__ float lrelu(float v) { return v > 0.0f ? v : NEGS * v; }

__device__ __forceinline__ void atomicMaxF(float* addr, float v) {
    if (v >= 0.0f) atomicMax((int*)addr, __float_as_int(v));
    else           atomicMin((unsigned int*)addr, __float_as_uint(v));
}

__device__ __forceinline__ void fma4(float4& a, float x, const float4 w) {
    a.x = fmaf(x, w.x, a.x); a.y = fmaf(x, w.y, a.y);
    a.z = fmaf(x, w.z, a.z); a.w = fmaf(x, w.w, a.w);
}

// ---- fused prep: WT packs + W5T transpose + gfeat init + transpose/sq0 + X zero-fill -----
constexpr int WTOT = 19072;
__global__ void k_prep_all(const float* __restrict__ W1, const float* __restrict__ W2,
                           const float* __restrict__ W3, const float* __restrict__ W4,
                           const float* __restrict__ W5, const float* __restrict__ x,
                           float4* __restrict__ WT4, float* __restrict__ W5T,
                           float* __restrict__ gfeat, float* __restrict__ X,
                           float* __restrict__ sq) {
    int j = blockIdx.x * blockDim.x + threadIdx.x;
    if (j < WTOT) {
        int base, Cout, C;
        const float* W;
        if (j < 128)       { base = 0;    Cout = 64;  C = 3;   W = W1; }
        else if (j < 2304) { base = 128;  Cout = 64;  C = 67;  W = W2; }
        else if (j < 6528) { base = 2304; Cout = 64;  C = 131; W = W3; }
        else               { base = 6528; Cout = 128; C = 195; W = W4; }
        int W4w = Cout / 2;                 // 2*Cout/4 float4 groups per channel row
        int local = j - base;
        int c = local / W4w, og = local - c * W4w;
        float v[4];
#pragma unroll
        for (int q = 0; q < 4; ++q) {
            int o2 = 4 * og + q;
            if (c >= C) v[q] = 0.f;
            else if (o2 < Cout) v[q] = W[(size_t)o2 * 2 * C + c];
            else {
                int o = o2 - Cout;
                v[q] = W[(size_t)o * 2 * C + C + c] - W[(size_t)o * 2 * C + c];
            }
        }
        WT4[j] = make_float4(v[0], v[1], v[2], v[3]);
    } else if (j < WTOT + XS * 1024) {
        int t = j - WTOT;
        int c = t / 1024, o = t % 1024;
        W5T[t] = (c < CT) ? W5[(size_t)o * CT + c] : 0.f;   // row 323 zeroed
    } else if (j < WTOT + XS * 1024 + BB * 1024) {
        gfeat[j - WTOT - XS * 1024] = -INFINITY;
    } else if (j < WTOT + XS * 1024 + BB * 1024 + BB * NN) {
        int i = j - WTOT - XS * 1024 - BB * 1024;            // b*NN + n
        int b = i >> 11, n = i & 2047;
        const float* xb = x + (size_t)b * 3 * NN;
        float vx = xb[n], vy = xb[NN + n], vz = xb[2 * NN + n];
        float* row = X + (size_t)i * XS;
        row[0] = vx; row[1] = vy; row[2] = vz; row[3] = 0.f;
        sq[i] = vx * vx + vy * vy + vz * vz;
    } else if (j < WTOT + XS * 1024 + BB * 1024 + BB * NN + BB * NN * 80) {
        // zero-fill X feature columns (float4 indices 1..80 of each row; col 3 done above)
        int t = j - (WTOT + XS * 1024 + BB * 1024 + BB * NN);
        int row = t / 80, c4 = 1 + (t - 80 * row);
        ((float4*)X)[(size_t)row * X4S + c4] = make_float4(0.f, 0.f, 0.f, 0.f);
    }
}

// ---- dist[b][n][m] = max(sq_n + sq_m - 2*dot, 0) — SYMMETRIC: only tiles ti>=tj ----------
// 128x128 tile, 8x8 per thread. Thread owns cols {tx*4..+3, 64+tx*4..+3}; B fragment is
// 2 ds_read_b128. Off-diagonal: direct float4 writes + mirrored 4-pass LDS transpose.
constexpr int TM = 128;
__global__ __launch_bounds__(256) void k_dist(const float* __restrict__ X,
                                              const float* __restrict__ sq,
                                              float* __restrict__ dist, int C) {
    int b = blockIdx.z;
    int blk = blockIdx.x;                 // 0..135 -> (ti, tj), ti >= tj
    int ti = (int)((sqrtf(8.0f * blk + 1.0f) - 1.0f) * 0.5f);
    while ((ti + 1) * (ti + 2) / 2 <= blk) ++ti;
    while (ti * (ti + 1) / 2 > blk) --ti;
    int tj = blk - ti * (ti + 1) / 2;
    int m0 = ti * TM;                     // col tile
    int n0 = tj * TM;                     // row tile
    __shared__ float smem[4352];          // 17 KB: staging (16 KB) / transpose T[32][129]
    float* AsB = smem;                    // As[16][TM]
    float* BsB = smem + 2048;             // Bs[16][TM]
    int tid = threadIdx.x;
    int tx = tid & 15;        // cols: m0 + h*64 + tx*4 + jj  (j = 4h+jj)
    int ty = tid >> 4;        // rows: n0 + ty*8 + i
    float acc[8][8] = {};
    const float* Xb = X + (size_t)b * NN * XS;
    int sr = tid & 127;       // staging row
    int sc0 = (tid >> 7) * 8; // staging channel half (0 or 8)
    for (int c0 = 0; c0 < C; c0 += 16) {
        const float* arow = Xb + (size_t)(n0 + sr) * XS + c0 + sc0;
        const float* brow = Xb + (size_t)(m0 + sr) * XS + c0 + sc0;
        float4 a0 = *(const float4*)(arow);
        float4 a1 = *(const float4*)(arow + 4);
        float4 b0 = *(const float4*)(brow);
        float4 b1 = *(const float4*)(brow + 4);
        float av[8] = {a0.x, a0.y, a0.z, a0.w, a1.x, a1.y, a1.z, a1.w};
        float bv8[8] = {b0.x, b0.y, b0.z, b0.w, b1.x, b1.y, b1.z, b1.w};
#pragma unroll
        for (int i = 0; i < 8; ++i) {
            bool inr = (c0 + sc0 + i) < C;
            AsB[(sc0 + i) * TM + sr] = inr ? av[i] : 0.f;
            BsB[(sc0 + i) * TM + sr] = inr ? bv8[i] : 0.f;
        }
        __syncthreads();
#pragma unroll
        for (int cc = 0; cc < 16; ++cc) {
            float4 a0r = *(const float4*)&AsB[cc * TM + ty * 8];
            float4 a1r = *(const float4*)&AsB[cc * TM + ty * 8 + 4];
            float a[8] = {a0r.x, a0r.y, a0r.z, a0r.w, a1r.x, a1r.y, a1r.z, a1r.w};
            float4 b0r = *(const float4*)&BsB[cc * TM + tx * 4];
            float4 b1r = *(const float4*)&BsB[cc * TM + 64 + tx * 4];
            float bv[8] = {b0r.x, b0r.y, b0r.z, b0r.w, b1r.x, b1r.y, b1r.z, b1r.w};
#pragma unroll
            for (int i = 0; i < 8; ++i)
#pragma unroll
                for (int j = 0; j < 8; ++j)
                    acc[i][j] = fmaf(a[i], bv[j], acc[i][j]);
        }
        __syncthreads();
    }
    const float* sqb = sq + b * NN;
    float* db = dist + (size_t)b * NN * NN;
    float sm[8];
#pragma unroll
    for (int j = 0; j < 8; ++j) sm[j] = sqb[m0 + (j >> 2) * 64 + tx * 4 + (j & 3)];
#pragma unroll
    for (int i = 0; i < 8; ++i) {
        int n = n0 + ty * 8 + i;
        float sn = sqb[n];
#pragma unroll
        for (int j = 0; j < 8; ++j) {
            float d = fmaxf(sn + sm[j] - 2.f * acc[i][j], 0.f);
            acc[i][j] = d;                                   // keep for mirror
        }
        *(float4*)&db[(size_t)n * NN + m0 + tx * 4] =
            make_float4(acc[i][0], acc[i][1], acc[i][2], acc[i][3]);
        *(float4*)&db[(size_t)n * NN + m0 + 64 + tx * 4] =
            make_float4(acc[i][4], acc[i][5], acc[i][6], acc[i][7]);
    }
    if (ti != tj) {
        // mirrored tile: rows m0.., cols n0.. — 4 passes (h: col half, p2: 32-row group)
        float* T = smem;                  // [32][129]
        int r = tid >> 3;                 // 0..31
        int c0r = (tid & 7) * 16;         // 0..112
#pragma unroll
        for (int h = 0; h < 2; ++h) {
#pragma unroll
            for (int p2 = 0; p2 < 2; ++p2) {
                __syncthreads();          // protect staging/previous pass reads
                if ((tx >> 3) == p2) {    // tx in [8*p2, 8*p2+8): m_local in [32p2, 32p2+32)
#pragma unroll
                    for (int jj = 0; jj < 4; ++jj)
#pragma unroll
                        for (int i = 0; i < 8; ++i)
                            T[((tx & 7) * 4 + jj) * 129 + ty * 8 + i] = acc[i][h * 4 + jj];
                }
                __syncthreads();
                float v[16];
#pragma unroll
                for (int k = 0; k < 16; ++k) v[k] = T[r * 129 + c0r + k];
                float* dst = db + (size_t)(m0 + h * 64 + 32 * p2 + r) * NN + n0 + c0r;
#pragma unroll
                for (int k = 0; k < 4; ++k)
                    *(float4*)(dst + 4 * k) = make_float4(v[4 * k], v[4 * k + 1],
                                                          v[4 * k + 2], v[4 * k + 3]);
            }
        }
    }
}

// ---- top-K smallest per row (SET semantics — downstream is max-pool, order-invariant) ----
// key = (bits(d)<<11)|m (unique; ties -> lower m, matching lax.top_k). Radix-select the
// exact 20th-smallest key T, then emit all keys <= T (exactly 20, arbitrary order).
__global__ __launch_bounds__(128) void k_select(const float* __restrict__ dist,
                                                int* __restrict__ idx) {
    int bn = blockIdx.x;   // b*NN + n
    int tid = threadIdx.x;
    int wv = tid >> 6;
    int lane = tid & 63;
    const float* drow = dist + (size_t)bn * NN;
    int m0 = tid * 16;
    unsigned long long keys[16];
#pragma unroll
    for (int i = 0; i < 4; ++i) {
        float4 v = *(const float4*)(drow + m0 + 4 * i);
        keys[4 * i + 0] = ((unsigned long long)__float_as_uint(v.x) << 11) | (unsigned)(m0 + 4 * i + 0);
        keys[4 * i + 1] = ((unsigned long long)__float_as_uint(v.y) << 11) | (unsigned)(m0 + 4 * i + 1);
        keys[4 * i + 2] = ((unsigned long long)__float_as_uint(v.z) << 11) | (unsigned)(m0 + 4 * i + 2);
        keys[4 * i + 3] = ((unsigned long long)__float_as_uint(v.w) << 11) | (unsigned)(m0 + 4 * i + 3);
    }
    // Bound B: per-lane min16 -> wave max of minima -> min over waves. Each wave has 64
    // keys (its lane minima) <= its own bound, so >=64 keys <= B => T(20th) <= B.
    unsigned long long mn = keys[0];
#pragma unroll
    for (int i = 1; i < 16; ++i) mn = keys[i] < mn ? keys[i] : mn;
    unsigned long long mx = mn;
#pragma unroll
    for (int s = 1; s < 64; s <<= 1) {
        unsigned long long o = (unsigned long long)__shfl_xor((long long)mx, s, 64);
        mx = o > mx ? o : mx;
    }
    __shared__ unsigned long long sB[2];
    __shared__ unsigned long long sT;
    __shared__ int sWant;
    __shared__ int sCnt;
    __shared__ int hist[256];
    if (lane == 0) sB[wv] = mx;
    if (tid == 0) { sT = 0ull; sWant = KK; sCnt = 0; }
    __syncthreads();
    unsigned long long B = sB[0] < sB[1] ? sB[0] : sB[1];
    // 6-level byte-wise radix descent over the 43-bit key (levels cover bits [47:0]).
#pragma unroll 1
    for (int level = 0; level < 6; ++level) {
        int sh = 40 - 8 * level;
        hist[tid] = 0; hist[tid + 128] = 0;
        __syncthreads();
        unsigned long long pref = sT;
#pragma unroll
        for (int i = 0; i < 16; ++i) {
            unsigned long long k = keys[i];
            if (k <= B && (k >> (sh + 8)) == (pref >> (sh + 8)))
                atomicAdd(&hist[(int)((k >> sh) & 255)], 1);
        }
        __syncthreads();
        if (tid < 64) {
            int h0 = hist[4 * tid], h1 = hist[4 * tid + 1];
            int h2 = hist[4 * tid + 2], h3 = hist[4 * tid + 3];
            int s = h0 + h1 + h2 + h3;
            int inc = s;
#pragma unroll
            for (int d = 1; d < 64; d <<= 1) {
                int o = __shfl_up(inc, d, 64);
                if (lane >= d) inc += o;
            }
            int want = sWant;
            int c = inc - s;              // exclusive prefix
            int bsel = -1, rem = 0;
            if (c < want && want <= c + h0) { bsel = 4 * tid + 0; rem = want - c; } c += h0;
            if (bsel < 0 && c < want && want <= c + h1) { bsel = 4 * tid + 1; rem = want - c; } c += h1;
            if (bsel < 0 && c < want && want <= c + h2) { bsel = 4 * tid + 2; rem = want - c; } c += h2;
            if (bsel < 0 && c < want && want <= c + h3) { bsel = 4 * tid + 3; rem = want - c; }
            if (bsel >= 0) {
                sT = pref | ((unsigned long long)bsel << sh);
                sWant = rem;
            }
        }
        __syncthreads();
    }
    unsigned long long T = sT;            // exact 20th-smallest key
    int* orow = idx + (size_t)bn * KK;
#pragma unroll
    for (int i = 0; i < 16; ++i) {
        if (keys[i] <= T) {
            int s = atomicAdd(&sCnt, 1);
            orow[s] = (int)(keys[i] & 2047u);
        }
    }
}

// ---- k_hg: H = X.Wa^T, G = X.Wd^T — dense GEMM, no gather. -------------------------------
template <int KC4, int COUT>
__global__ __launch_bounds__(256)
void k_hg(const float* __restrict__ X, const float4* __restrict__ WT4,
          float* __restrict__ H, float* __restrict__ G) {
    constexpr int W4 = COUT / 2;            // 2*COUT/4 float4 outputs per channel row
    constexpr int RB2 = 32;
    constexpr int RPT = RB2 * W4 / 256;     // rows per thread (8 for COUT=128, 4 for 64)
    int bn0 = blockIdx.x * RB2;
    __shared__ float4 xs[RB2][KC4];
    int tid = threadIdx.x;
    const float4* X4 = (const float4*)X;
    for (int j = tid; j < RB2 * KC4; j += 256) {
        int r = j / KC4, c = j - r * KC4;
        xs[r][c] = X4[(size_t)(bn0 + r) * X4S + c];
    }
    __syncthreads();
    int og = tid & (W4 - 1);
    int rg = tid / W4;                      // row group
    float4 acc[RPT];
#pragma unroll
    for (int i = 0; i < RPT; ++i) acc[i] = make_float4(0.f, 0.f, 0.f, 0.f);
#pragma unroll 2
    for (int c4 = 0; c4 < KC4; ++c4) {
        float4 w0 = WT4[(size_t)(4 * c4 + 0) * W4 + og];
        float4 w1 = WT4[(size_t)(4 * c4 + 1) * W4 + og];
        float4 w2 = WT4[(size_t)(4 * c4 + 2) * W4 + og];
        float4 w3 = WT4[(size_t)(4 * c4 + 3) * W4 + og];
#pragma unroll
        for (int i = 0; i < RPT; ++i) {
            float4 xv = xs[rg * RPT + i][c4];
            fma4(acc[i], xv.x, w0);
            fma4(acc[i], xv.y, w1);
            fma4(acc[i], xv.z, w2);
            fma4(acc[i], xv.w, w3);
        }
    }
    int o2 = 4 * og;
#pragma unroll
    for (int i = 0; i < RPT; ++i) {
        int bn = bn0 + rg * RPT + i;
        if (o2 < COUT) *(float4*)&H[(size_t)bn * COUT + o2] = acc[i];
        else           *(float4*)&G[(size_t)bn * COUT + (o2 - COUT)] = acc[i];
    }
}

// ---- k_edgemax: X[bn, outoff+o] = max_k lrelu((H[idx[bn,k],o] + G[bn,o])*s+b) ------------
template <int COUT>
__global__ __launch_bounds__(256)
void k_edgemax(const float* __restrict__ H, const float* __restrict__ G,
               const int* __restrict__ idx, const float* __restrict__ scale,
               const float* __restrict__ bias, int outoff,
               float* __restrict__ X, float* __restrict__ sq) {
    constexpr int CPL = COUT / 64;          // cols per lane (1 or 2)
    int wv = threadIdx.x >> 6, lane = threadIdx.x & 63;
    int bn = blockIdx.x * 4 + wv;
    int b = bn >> 11;                       // NN = 2048
    int id = idx[(size_t)bn * KK + (lane < KK ? lane : 0)];
    float gv[CPL], sv[CPL], bv[CPL], mx[CPL];
#pragma unroll
    for (int q = 0; q < CPL; ++q) {
        int o = lane + 64 * q;
        gv[q] = G[(size_t)bn * COUT + o];
        sv[q] = scale[o];
        bv[q] = bias[o];
        mx[q] = -INFINITY;
    }
#pragma unroll
    for (int k = 0; k < KK; ++k) {
        int m = __shfl(id, k, 64);
        const float* hrow = H + (size_t)(b * NN + m) * COUT;
#pragma unroll
        for (int q = 0; q < CPL; ++q) {
            float v = hrow[lane + 64 * q] + gv[q];
            mx[q] = fmaxf(mx[q], lrelu(v * sv[q] + bv[q]));
        }
    }
    float* orow = X + (size_t)bn * XS + outoff;
    float v = 0.f;
#pragma unroll
    for (int q = 0; q < CPL; ++q) {
        orow[lane + 64 * q] = mx[q];
        v = fmaf(mx[q], mx[q], v);
    }
#pragma unroll
    for (int s = 1; s < 64; s <<= 1) v += __shfl_xor(v, s, 64);
    if (lane == 0) sq[bn] += v;
}

// ---- block5: g = lrelu((X . W5^T)*s5+b5), atomic max over n into gfeat -------------------
// R24 (kept): wave-uniform global X reads via readfirstlane (scalar pipe), LDS=0.
constexpr int RB = 32;
__global__ __launch_bounds__(512) void k_stage5(const float* __restrict__ X,
                                                const float* __restrict__ W5T,
                                                const float* __restrict__ s5,
                                                const float* __restrict__ b5,
                                                float* __restrict__ gfeat) {
    int blk = blockIdx.x;
    int b = blk / (NN / RB);
    int n0 = (blk % (NN / RB)) * RB;
    int tid = threadIdx.x;
    const float4* X4 = (const float4*)X;
    const float4* W5T4 = (const float4*)W5T;   // [XS][256] float4 per row
    int og = tid & 255;                   // output float4 slot (4 outputs)
    int r0 = __builtin_amdgcn_readfirstlane((tid >> 8) * 16);  // wave-uniform row group
    const float4* xrows = X4 + (size_t)(b * NN + n0 + r0) * X4S;
    float acc[16][4] = {};
    for (int c4 = 0; c4 < X4S; ++c4) {
        float4 w0 = W5T4[(size_t)(4 * c4 + 0) * 256 + og];
        float4 w1 = W5T4[(size_t)(4 * c4 + 1) * 256 + og];
        float4 w2 = W5T4[(size_t)(4 * c4 + 2) * 256 + og];
        float4 w3 = W5T4[(size_t)(4 * c4 + 3) * 256 + og];
#pragma unroll
        for (int r = 0; r < 16; ++r) {
            float4 a = xrows[(size_t)r * X4S + c4];   // uniform addr -> scalar load
            acc[r][0] = fmaf(a.x, w0.x, acc[r][0]);
            acc[r][1] = fmaf(a.x, w0.y, acc[r][1]);
            acc[r][2] = fmaf(a.x, w0.z, acc[r][2]);
            acc[r][3] = fmaf(a.x, w0.w, acc[r][3]);
            acc[r][0] = fmaf(a.y, w1.x, acc[r][0]);
            acc[r][1] = fmaf(a.y, w1.y, acc[r][1]);
            acc[r][2] = fmaf(a.y, w1.z, acc[r][2]);
            acc[r][3] = fmaf(a.y, w1.w, acc[r][3]);
            acc[r][0] = fmaf(a.z, w2.x, acc[r][0]);
            acc[r][1] = fmaf(a.z, w2.y, acc[r][1]);
            acc[r][2] = fmaf(a.z, w2.z, acc[r][2]);
            acc[r][3] = fmaf(a.z, w2.w, acc[r][3]);
            acc[r][0] = fmaf(a.w, w3.x, acc[r][0]);
            acc[r][1] = fmaf(a.w, w3.y, acc[r][1]);
            acc[r][2] = fmaf(a.w, w3.z, acc[r][2]);
            acc[r][3] = fmaf(a.w, w3.w, acc[r][3]);
        }
    }
    int o0 = og * 4;
#pragma unroll
    for (int i = 0; i < 4; ++i) {
        int o = o0 + i;
        float s = s5[o], bbv = b5[o];
        float mx = -INFINITY;
#pragma unroll
        for (int r = 0; r < 16; ++r) {
            float v = lrelu(acc[r][i] * s + bbv);
            mx = fmaxf(v, mx);
        }
        atomicMaxF(&gfeat[b * 1024 + o], mx);
    }
}

// ---- fused FC head: fc1 -> fc2 -> fc3 per batch row, intermediates in LDS ----------------
__global__ __launch_bounds__(256) void k_fc(const float* __restrict__ gfeat,
                                            const float* __restrict__ fW1, const float* __restrict__ fb1,
                                            const float* __restrict__ fs1, const float* __restrict__ fB1,
                                            const float* __restrict__ fW2, const float* __restrict__ fb2,
                                            const float* __restrict__ fs2, const float* __restrict__ fB2,
                                            const float* __restrict__ fW3, const float* __restrict__ fb3,
                                            float* __restrict__ logits) {
    int b = blockIdx.x;
    __shared__ float g[1024];
    __shared__ float h1s[512];
    __shared__ float h2s[256];
    int tid = threadIdx.x;
    for (int j = tid; j < 1024; j += 256) g[j] = gfeat[b * 1024 + j];
    __syncthreads();
    for (int o = tid; o < 512; o += 256) {
        const float* wr = fW1 + (size_t)o * 1024;
        float acc = 0.f;
        for (int c = 0; c < 1024; ++c) acc = fmaf(g[c], wr[c], acc);
        h1s[o] = lrelu((acc + fb1[o]) * fs1[o] + fB1[o]);
    }
    __syncthreads();
    {
        int o = tid;
        const float* wr = fW2 + (size_t)o * 512;
        float acc = 0.f;
        for (int c = 0; c < 512; ++c) acc = fmaf(h1s[c], wr[c], acc);
        h2s[o] = lrelu((acc + fb2[o]) * fs2[o] + fB2[o]);
    }
    __syncthreads();
    if (tid < 40) {
        const float* wr = fW3 + (size_t)tid * 256;
        float acc = 0.f;
        for (int c = 0; c < 256; ++c) acc = fmaf(h2s[c], wr[c], acc);
        logits[b * 40 + tid] = acc + fb3[tid];
    }
}

extern "C" void kernel_launch(void* const* d_in, const int* in_sizes, int n_in,
                              void* d_out, int out_size, void* d_ws, size_t ws_size,
                              hipStream_t stream) {
    const float* x   = (const float*)d_in[0];
    const float* W1  = (const float*)d_in[1];
    const float* s1  = (const float*)d_in[2];
    const float* b1  = (const float*)d_in[3];
    const float* W2  = (const float*)d_in[4];
    const float* s2  = (const float*)d_in[5];
    const float* b2  = (const float*)d_in[6];
    const float* W3  = (const float*)d_in[7];
    const float* s3  = (const float*)d_in[8];
    const float* b3  = (const float*)d_in[9];
    const float* W4  = (const float*)d_in[10];
    const float* s4  = (const float*)d_in[11];
    const float* b4  = (const float*)d_in[12];
    const float* W5  = (const float*)d_in[13];
    const float* s5  = (const float*)d_in[14];
    const float* b5  = (const float*)d_in[15];
    const float* fW1 = (const float*)d_in[16];
    const float* fb1 = (const float*)d_in[17];
    const float* fs1 = (const float*)d_in[18];
    const float* fB1 = (const float*)d_in[19];
    const float* fW2 = (const float*)d_in[20];
    const float* fb2 = (const float*)d_in[21];
    const float* fs2 = (const float*)d_in[22];
    const float* fB2 = (const float*)d_in[23];
    const float* fW3 = (const float*)d_in[24];
    const float* fb3 = (const float*)d_in[25];

    float* out    = (float*)d_out;
    float* logits = out;          // 8*40
    float* gfeat  = out + 320;    // 8*1024

    char* ws = (char*)d_ws;
    size_t off = 0;
    auto alloc = [&](size_t bytes) -> void* {
        void* p = ws + off;
        off += (bytes + 255) & ~(size_t)255;
        return p;
    };
    float* X    = (float*)alloc((size_t)BB * NN * XS * 4);      // 21.2 MB
    float* sq   = (float*)alloc((size_t)BB * NN * 4);
    float* dist = (float*)alloc((size_t)BB * NN * NN * 4);      // 134 MB
    int*   idx  = (int*)  alloc((size_t)BB * NN * KK * 4);
    float4* WT4 = (float4*)alloc((size_t)WTOT * 16);            // 305 KB
    float* H    = (float*)alloc((size_t)BB * NN * 128 * 4);     // 8.4 MB
    float* G    = (float*)alloc((size_t)BB * NN * 128 * 4);     // 8.4 MB
    float* W5T  = (float*)alloc((size_t)XS * 1024 * 4);
    (void)ws_size; (void)in_sizes; (void)n_in; (void)out_size;

    // one-shot prep: WT packs + W5T + gfeat init + transpose/sq0 + X zero-fill
    int prepTot = WTOT + XS * 1024 + BB * 1024 + BB * NN + BB * NN * 80;
    k_prep_all<<<(prepTot + 255) / 256, 256, 0, stream>>>(W1, W2, W3, W4, W5, x,
                                                          WT4, W5T, gfeat, X, sq);

    const int Cs[4]    = {3, 67, 131, 195};
    const int offs[4]  = {3, 67, 131, 195};
    const int WOFF[4]  = {0, 128, 2304, 6528};  // channel-row base in packed WT4
    const float* ss[4] = {s1, s2, s3, s4};
    const float* bs[4] = {b1, b2, b3, b4};

    constexpr int NT = NN / TM;                 // 16 tiles per dim
    constexpr int NBLK = NT * (NT + 1) / 2;     // 136 lower-triangle tiles
    for (int st = 0; st < 4; ++st) {
        int C = Cs[st];
        dim3 dg(NBLK, 1, BB);
        k_dist<<<dg, 256, 0, stream>>>(X, sq, dist, C);
        k_select<<<BB * NN, 128, 0, stream>>>(dist, idx);
        const float4* wt = WT4 + WOFF[st];
        switch (st) {
            case 0:
                k_hg<1, 64><<<BB * NN / 32, 256, 0, stream>>>(X, wt, H, G);
                k_edgemax<64><<<BB * NN / 4, 256, 0, stream>>>(H, G, idx, ss[st], bs[st], offs[st], X, sq);
                break;
            case 1:
                k_hg<17, 64><<<BB * NN / 32, 256, 0, stream>>>(X, wt, H, G);
                k_edgemax<64><<<BB * NN / 4, 256, 0, stream>>>(H, G, idx, ss[st], bs[st], offs[st], X, sq);
                break;
            case 2:
                k_hg<33, 64><<<BB * NN / 32, 256, 0, stream>>>(X, wt, H, G);
                k_edgemax<64><<<BB * NN / 4, 256, 0, stream>>>(H, G, idx, ss[st], bs[st], offs[st], X, sq);
                break;
            case 3:
                k_hg<49, 128><<<BB * NN / 32, 256, 0, stream>>>(X, wt, H, G);
                k_edgemax<128><<<BB * NN / 4, 256, 0, stream>>>(H, G, idx, ss[st], bs[st], offs[st], X, sq);
                break;
        }
    }

    k_stage5<<<BB * (NN / RB), 512, 0, stream>>>(X, W5T, s5, b5, gfeat);
    k_fc<<<BB, 256, 0, stream>>>(gfeat, fW1, fb1, fs1, fB1,
                                 fW2, fb2, fs2, fB2, fW3, fb3, logits);
}